// Round 21
// baseline (59.013 us; speedup 1.0000x reference)
//
#include <hip/hip_runtime.h>
#include <hip/hip_bf16.h>

// Problem constants
#define B_ROWS 4096
#define NN     8192
#define DD     128
#define NTRI   2080         // 64*65/2 upper-triangular tiles
#define NB     512          // resident blocks: exactly 2 per CU
#define CSHIFT 128.0f       // fixed logsumexp shift (log2 domain)

typedef __attribute__((ext_vector_type(8))) short s8v;   // 8 bf16 (4 VGPR)
typedef __attribute__((ext_vector_type(4))) float f4v;   // 4 f32
typedef __attribute__((ext_vector_type(2))) float f2v;
typedef unsigned int u32;
typedef unsigned short u16;
typedef unsigned char u8;

static constexpr float SCALE_H = 1.6986436f;      // sqrt(2*log2(e)); folds /TEMP and log2e into the matmul
static constexpr float SCALE2  = 2.8853900818f;   // 2*log2(e)
static constexpr float LN2     = 0.6931471805599453f;
static constexpr float INV255  = 1.0f / 255.0f;

__device__ __forceinline__ float fast_exp2(float x) {
#if __has_builtin(__builtin_amdgcn_exp2f)
    return __builtin_amdgcn_exp2f(x);      // bare v_exp_f32
#else
    return exp2f(x);
#endif
}

// (1 - x^2) with mask folded in, quantized to u8 (max err 1/510 on s2)
__device__ __forceinline__ u8 s2m_pack8(float x, bool msk) {
    float s2 = msk ? 0.f : 1.f - x * x;    // s2=0 => exp2(-CSHIFT) -> ~0
    return (u8)(s2 * 255.f + 0.5f);
}

__device__ __forceinline__ u16 f2bf(float x) {
    union { __hip_bfloat16 h; u16 u; } cv;
    cv.h = __float2bfloat16(x);
    return cv.u;
}

__device__ __forceinline__ float bf2f(u16 u) {
    return __uint_as_float(((u32)u) << 16);
}

typedef __attribute__((address_space(1))) const u32 gu32;
typedef __attribute__((address_space(3))) u32 lu32;
__device__ __forceinline__ void gload_lds16(const void* g, void* l) {
    // async global->LDS, 16B/lane; dest = lds base + lane*16 (wave-uniform base)
    __builtin_amdgcn_global_load_lds((gu32*)g, (lu32*)l, 16, 0, 0);
}

// triangular decode: bid -> (i,j), i <= j  (exact after integer fixup)
#define DECODE(BID, I, J) do {                                         \
    int _b = (BID);                                                    \
    int _j = (int)((sqrtf(8.f * (float)_b + 1.f) - 1.f) * 0.5f);       \
    while (((_j + 1) * (_j + 2)) / 2 <= _b) ++_j;                      \
    while ((_j * (_j + 1)) / 2 > _b) --_j;                             \
    (J) = _j; (I) = _b - (_j * (_j + 1)) / 2;                          \
} while (0)

// ---- kernel 1: fused bf16-prep + pos dot ----
__global__ void hpos_kernel(const float* __restrict__ hi, const float* __restrict__ hj,
                            __hip_bfloat16* __restrict__ hb, float* __restrict__ pos2) {
    int w = threadIdx.x >> 6, l = threadIdx.x & 63;
    int row = blockIdx.x * 4 + w;
    f2v a = ((const f2v*)(hi + (size_t)row * DD))[l];
    f2v b = ((const f2v*)(hj + (size_t)row * DD))[l];
    float d = a[0] * b[0] + a[1] * b[1];
    #pragma unroll
    for (int off = 32; off; off >>= 1) d += __shfl_xor(d, off, 64);
    if (l == 0) pos2[row] = SCALE2 * d;
    union { ushort2 u2; __hip_bfloat16 h[2]; } ua, ub;
    ua.h[0] = __float2bfloat16(a[0] * SCALE_H);
    ua.h[1] = __float2bfloat16(a[1] * SCALE_H);
    ub.h[0] = __float2bfloat16(b[0] * SCALE_H);
    ub.h[1] = __float2bfloat16(b[1] * SCALE_H);
    ((ushort2*)(hb + (size_t)row * DD))[l] = ua.u2;
    ((ushort2*)(hb + (size_t)(row + B_ROWS) * DD))[l] = ub.u2;
}

// ---- kernel 2: resident pipelined symmetric-tile kernel ----
// 512 blocks (2/CU, all co-resident), each sweeps 4-5 consecutive triangular
// tiles. Per tile t: [barrier] -> issue BSTAGE(t+1)+SLOAD(t+1) -> afr(t) ->
// MFMA(t) -> epilogue(t) (exp2 VALU covers S(t+1) latency) -> SPACK(t+1) ->
// direct global partial stores. LDS dbuf: 2x(32KB B + 8KB u8 panels) = 80 KB.
__global__ __launch_bounds__(512, 4)
void main_kernel(const __hip_bfloat16* __restrict__ hb, const float* __restrict__ S,
                 u16* __restrict__ ssr, u16* __restrict__ ssc) {
    __shared__ short ldsB[2][128][128];               // 64 KB B tiles (row-swizzled)
    __shared__ __align__(16) u8 sAu[2][4096];         // 8 KB row-view s2m (u8)
    __shared__ __align__(16) u8 sBtu[2][4096];        // 8 KB col-view s2m, transposed

    // XCD-contiguous remap (512 = 8 x 64), then tile range [start, start+cnt)
    const int orig = blockIdx.x;
    const int rb   = (orig & 7) * 64 + (orig >> 3);
    const int start = (rb * NTRI) >> 9;               // floor(rb * 4.0625)
    const int cnt   = (((rb + 1) * NTRI) >> 9) - start;   // 4 or 5

    const int tid = threadIdx.x;
    const int l  = tid & 63;
    const int w  = tid >> 6;                   // 0..7
    const int wm = w >> 1, wn = w & 1;
    const int lc = l & 15;                     // frag row/col within 16
    const int lk = l >> 4;                     // k-group
    const int prr = tid >> 3;                  // 0..63 (panel row)
    const int pc8 = (tid & 7) * 8;             // 0..56 (panel col base)

    const s8v* hb8 = (const s8v*)hb;           // 16 x s8v per row of 128 bf16

#define BSTAGE(P, J) do {                                                         \
    _Pragma("unroll")                                                             \
    for (int i2 = 0; i2 < 4; i2++) {                                              \
        const int rowb = w * 16 + i2 * 4;                                         \
        const int lrw  = rowb + lk;            /* local row 0..127 */             \
        const int grow = (J) * 64 + ((lrw < 64) ? lrw : (lrw - 64 + B_ROWS));     \
        const int sc16 = lc ^ (lrw & 7);       /* source pre-swizzle */           \
        gload_lds16((const char*)hb + ((size_t)grow << 8) + (sc16 << 4),          \
                    (char*)&ldsB[P][rowb][0]);                                    \
    }                                                                             \
} while (0)

#define SLOAD(I, J, A0, A1, B0, B1) do {                                          \
    const float* _gA = S + (size_t)((I) * 64 + prr) * B_ROWS + (J) * 64 + pc8;    \
    const float* _gB = S + (size_t)((J) * 64 + prr) * B_ROWS + (I) * 64 + pc8;    \
    A0 = ((const f4v*)_gA)[0]; A1 = ((const f4v*)_gA)[1];                         \
    B0 = ((const f4v*)_gB)[0]; B1 = ((const f4v*)_gB)[1];                         \
} while (0)

#define SPACK(P, I, J, A0, A1, B0, B1) do {                                       \
    const bool _dg = ((I) == (J));                                                \
    union { u8 c[8]; uint2 v; } _qa;                                              \
    u8 _qb[8];                                                                    \
    _Pragma("unroll")                                                             \
    for (int e = 0; e < 4; e++) {                                                 \
        _qa.c[e]     = s2m_pack8(A0[e], _dg && (pc8 + e     == prr));             \
        _qa.c[e + 4] = s2m_pack8(A1[e], _dg && (pc8 + 4 + e == prr));             \
        _qb[e]     = s2m_pack8(B0[e], false);                                     \
        _qb[e + 4] = s2m_pack8(B1[e], false);                                     \
    }                                                                             \
    *(uint2*)&sAu[P][prr * 64 + pc8] = _qa.v;                                     \
    _Pragma("unroll")                                                             \
    for (int e = 0; e < 8; e++)                                                   \
        sBtu[P][(pc8 + e) * 64 + prr] = _qb[e];                                   \
} while (0)

    // ---- prologue: decode + stage tile 0
    int ci, cj;
    DECODE(start, ci, cj);
    BSTAGE(0, cj);
    {
        f4v a0, a1, b0, b1;
        SLOAD(ci, cj, a0, a1, b0, b1);
        SPACK(0, ci, cj, a0, a1, b0, b1);
    }

    for (int t = 0; t < cnt; ++t) {
        const int p = t & 1;
        __syncthreads();   // ldsB[p] + panels[p] ready (drains stage + stores)

        const bool hn = (t + 1 < cnt);
        int ni = ci, nj = cj;
        f4v na0, na1, nb0, nb1;
        if (hn) {
            DECODE(start + t + 1, ni, nj);
            BSTAGE(1 - p, nj);                 // async into other buffer
            SLOAD(ni, nj, na0, na1, nb0, nb1); // in flight during MFMA+epilogue
        }

        // A fragments for current tile (L2-warm)
        s8v afr[2][4];
        #pragma unroll
        for (int fm = 0; fm < 2; fm++) {
            int ar = (ci * 64 + wm * 16 + lc) + fm * B_ROWS;
            #pragma unroll
            for (int kk = 0; kk < 4; kk++)
                afr[fm][kk] = hb8[ar * 16 + kk * 4 + lk];
        }

        // ---- MFMA: 32 per wave, acc[fm][fh][cg]
        const char* bp[4];
        {
            const char* bb = (const char*)&ldsB[p][0][0] + (wn * 32 + lc) * 256;
            #pragma unroll
            for (int kk = 0; kk < 4; kk++)
                bp[kk] = bb + (((kk * 4 + lk) ^ (lc & 7)) << 4);
        }
        f4v acc[2][2][2];
        #pragma unroll
        for (int fm = 0; fm < 2; fm++)
            #pragma unroll
            for (int fh = 0; fh < 2; fh++)
                #pragma unroll
                for (int cg = 0; cg < 2; cg++) acc[fm][fh][cg] = f4v{0.f, 0.f, 0.f, 0.f};
        #pragma unroll
        for (int kk = 0; kk < 4; kk++) {
            #pragma unroll
            for (int fh = 0; fh < 2; fh++)
                #pragma unroll
                for (int cg = 0; cg < 2; cg++) {
                    s8v bf = *(const s8v*)(bp[kk] + fh * 16384 + cg * 4096);
                    acc[0][fh][cg] = __builtin_amdgcn_mfma_f32_16x16x32_bf16(
                        afr[0][kk], bf, acc[0][fh][cg], 0, 0, 0);
                    acc[1][fh][cg] = __builtin_amdgcn_mfma_f32_16x16x32_bf16(
                        afr[1][kk], bf, acc[1][fh][cg], 0, 0, 0);
                }
        }

        // ---- dual epilogue (exp2 VALU; covers S(t+1) load latency)
        float rsum[2][4], csum[2][2];
        #pragma unroll
        for (int fm = 0; fm < 2; fm++)
            #pragma unroll
            for (int r = 0; r < 4; r++) rsum[fm][r] = 0.f;
        csum[0][0] = csum[0][1] = csum[1][0] = csum[1][1] = 0.f;

        #pragma unroll
        for (int r = 0; r < 4; r++) {
            const int rr = wm * 16 + lk * 4 + r;
            #pragma unroll
            for (int cg = 0; cg < 2; cg++) {
                const int cc = wn * 32 + cg * 16 + lc;
                const float s2a = (float)sAu[p][rr * 64 + cc] * INV255;
                const float s2b = (float)sBtu[p][rr * 64 + cc] * INV255;
                #pragma unroll
                for (int fm = 0; fm < 2; fm++)
                    #pragma unroll
                    for (int fh = 0; fh < 2; fh++) {
                        const float a = acc[fm][fh][cg][r];
                        rsum[fm][r]  += fast_exp2(fmaf(a, s2a, -CSHIFT));
                        csum[fh][cg] += fast_exp2(fmaf(a, s2b, -CSHIFT));
                    }
            }
        }

        // ---- pack next tile's panels (S loads have had MFMA+epilogue to land)
        if (hn) SPACK(1 - p, ni, nj, na0, na1, nb0, nb1);

        // ---- per-wave reduce + direct global bf16 stores
        #pragma unroll
        for (int fm = 0; fm < 2; fm++) {
            #pragma unroll
            for (int r = 0; r < 4; r++) {
                float ss = rsum[fm][r];
                #pragma unroll
                for (int off = 1; off < 16; off <<= 1) ss += __shfl_xor(ss, off, 64);
                if (lc == 0) {
                    int rho = wm * 16 + lk * 4 + r;
                    ssr[(size_t)(cj * 2 + wn) * NN + (ci * 64 + rho + fm * B_ROWS)] = f2bf(ss);
                }
            }
        }
        #pragma unroll
        for (int fh = 0; fh < 2; fh++) {
            #pragma unroll
            for (int cg = 0; cg < 2; cg++) {
                float ss = csum[fh][cg];
                ss += __shfl_xor(ss, 16, 64);
                ss += __shfl_xor(ss, 32, 64);
                if (l < 16) {
                    int cc = wn * 32 + cg * 16 + lc;
                    ssc[(size_t)(ci * 4 + wm) * NN + (cj * 64 + cc + fh * B_ROWS)] = f2bf(ss);
                }
            }
        }
        ci = ni; cj = nj;
    }
#undef BSTAGE
#undef SLOAD
#undef SPACK
}

// ---- kernel 3a: parallel split-sum + lse (R19, proven) ----
__global__ __launch_bounds__(256)
void reduce_kernel(const u16* __restrict__ ssr, const u16* __restrict__ ssc,
                   const float* __restrict__ pos2, float* __restrict__ partial) {
    __shared__ float red[256];
    const int r = threadIdx.x & 31;
    const int s = threadIdx.x >> 5;
    const int n = blockIdx.x * 32 + r;              // n < 8192
    const int it = (n & (B_ROWS - 1)) >> 6;         // tile index of this row
    float ssum = 0.f;
    for (int sp = 2 * it + s; sp < 128; sp += 8)
        ssum += bf2f(ssr[(size_t)sp * NN + n]);
    for (int sp = s; sp < 4 * it; sp += 8)
        ssum += bf2f(ssc[(size_t)sp * NN + n]);
    red[threadIdx.x] = ssum;
    __syncthreads();
    if (threadIdx.x < 32) {
        float t = 0.f;
        #pragma unroll
        for (int k = 0; k < 8; k++) t += red[threadIdx.x + 32 * k];
        float p = pos2[n & (B_ROWS - 1)];
        float Ssum = t + fast_exp2(p - CSHIFT);     // pos logit seeds the sum
        red[threadIdx.x] = (CSHIFT + log2f(Ssum)) - p;  // log2 units
    }
    __syncthreads();
    if (threadIdx.x == 0) {
        float acc = 0.f;
        #pragma unroll
        for (int k = 0; k < 32; k++) acc += red[k];
        partial[blockIdx.x] = acc;
    }
}

// ---- kernel 3b: deterministic final sum over 256 partials (LDS tree) ----
__global__ __launch_bounds__(256)
void final_kernel(const float* __restrict__ partial, float* __restrict__ out) {
    __shared__ float red[256];
    red[threadIdx.x] = partial[threadIdx.x];
    __syncthreads();
    for (int st = 128; st; st >>= 1) {
        if (threadIdx.x < st) red[threadIdx.x] += red[threadIdx.x + st];
        __syncthreads();
    }
    if (threadIdx.x == 0) out[0] = red[0] * (LN2 / (float)NN);
}

extern "C" void kernel_launch(void* const* d_in, const int* in_sizes, int n_in,
                              void* d_out, int out_size, void* d_ws, size_t ws_size,
                              hipStream_t stream) {
    (void)in_sizes; (void)n_in; (void)out_size; (void)ws_size;
    const float* hi = (const float*)d_in[0];
    const float* hj = (const float*)d_in[1];
    const float* S  = (const float*)d_in[2];

    char* ws = (char*)d_ws;
    __hip_bfloat16* hb = (__hip_bfloat16*)ws;                        // 2 MB
    float* pos2   = (float*)(ws + 2097152);                          // 16 KB
    u16*   ssr    = (u16*)(ws + 2097152 + 16384);                    // 2 MB (128 splits bf16)
    u16*   ssc    = (u16*)(ws + 2097152 + 16384 + 2097152);          // 4 MB (256 splits bf16)
    float* partial= (float*)(ws + 2097152 + 16384 + 2097152 + 4194304); // 1 KB

    hpos_kernel<<<1024, 256, 0, stream>>>(hi, hj, hb, pos2);
    main_kernel<<<NB, 512, 0, stream>>>(hb, S, ssr, ssc);
    reduce_kernel<<<256, 256, 0, stream>>>(ssr, ssc, pos2, partial);
    final_kernel<<<1, 256, 0, stream>>>(partial, (float*)d_out);
}

// Round 22
// 43.542 us; speedup vs baseline: 1.3553x; 1.3553x over previous
//
#include <hip/hip_runtime.h>
#include <hip/hip_bf16.h>

// Problem constants
#define B_ROWS 4096
#define NN     8192
#define DD     128
#define NSPLIT 64           // split s of row n = the "other" tile index
#define NTRI   2080         // 64*65/2 upper-triangular tiles
#define SPA    68           // s2m panel row stride in u16 (136 B, 8B-aligned stores)
#define CSHIFT 128.0f       // fixed logsumexp shift (log2 domain)

typedef __attribute__((ext_vector_type(8))) short s8v;   // 8 bf16 (4 VGPR)
typedef __attribute__((ext_vector_type(4))) float f4v;   // 4 f32
typedef __attribute__((ext_vector_type(2))) float f2v;
typedef __attribute__((ext_vector_type(4))) unsigned short u16x4;
typedef unsigned int u32;

static constexpr float SCALE_H = 1.6986436f;      // sqrt(2*log2(e)); folds /TEMP and log2e into the matmul
static constexpr float SCALE2  = 2.8853900818f;   // 2*log2(e)
static constexpr float LN2     = 0.6931471805599453f;

__device__ __forceinline__ float fast_exp2(float x) {
#if __has_builtin(__builtin_amdgcn_exp2f)
    return __builtin_amdgcn_exp2f(x);      // bare v_exp_f32
#else
    return exp2f(x);
#endif
}

// (1 - x^2) with mask folded in, rounded to bf16 bits
__device__ __forceinline__ unsigned short s2m_pack(float x, bool msk) {
    float s2 = msk ? 0.f : 1.f - x * x;    // s2m=0 => exp2(-CSHIFT) -> ~0
    union { __hip_bfloat16 h; unsigned short u; } cv;
    cv.h = __float2bfloat16(s2);
    return cv.u;
}

__device__ __forceinline__ float bf16f(unsigned short u) {
    return __uint_as_float(((u32)u) << 16);
}

typedef __attribute__((address_space(1))) const u32 gu32;
typedef __attribute__((address_space(3))) u32 lu32;
__device__ __forceinline__ void gload_lds16(const void* g, void* l) {
    // async global->LDS, 16B/lane; dest = lds base + lane*16 (wave-uniform base)
    __builtin_amdgcn_global_load_lds((gu32*)g, (lu32*)l, 16, 0, 0);
}

// ---- kernel 1: fused bf16-prep + pos dot ----
__global__ void hpos_kernel(const float* __restrict__ hi, const float* __restrict__ hj,
                            __hip_bfloat16* __restrict__ hb, float* __restrict__ pos2) {
    int w = threadIdx.x >> 6, l = threadIdx.x & 63;
    int row = blockIdx.x * 4 + w;
    f2v a = ((const f2v*)(hi + (size_t)row * DD))[l];
    f2v b = ((const f2v*)(hj + (size_t)row * DD))[l];
    float d = a[0] * b[0] + a[1] * b[1];
    #pragma unroll
    for (int off = 32; off; off >>= 1) d += __shfl_xor(d, off, 64);
    if (l == 0) pos2[row] = SCALE2 * d;
    union { ushort2 u2; __hip_bfloat16 h[2]; } ua, ub;
    ua.h[0] = __float2bfloat16(a[0] * SCALE_H);
    ua.h[1] = __float2bfloat16(a[1] * SCALE_H);
    ub.h[0] = __float2bfloat16(b[0] * SCALE_H);
    ub.h[1] = __float2bfloat16(b[1] * SCALE_H);
    ((ushort2*)(hb + (size_t)row * DD))[l] = ua.u2;
    ((ushort2*)(hb + (size_t)(row + B_ROWS) * DD))[l] = ub.u2;
}

// ---- kernel 2: symmetric-tile fused sim*S2 + fixed-shift sum-of-exp2 ----
// (R16 verbatim -- best measured configuration: 42.3 us, 50% occ, no spill)
// Grid = 2080 live triangular tiles; XCD-bijective swizzle; dual epilogue.
__global__ __launch_bounds__(512, 4)
void main_kernel(const __hip_bfloat16* __restrict__ hb, const float* __restrict__ S,
                 float* __restrict__ ssplit) {
    __shared__ short ldsB[128][128];           // 32 KB B tile (row-swizzled)
    __shared__ unsigned short sA[64][SPA];     // 8.5 KB row-view s2m (bf16)
    __shared__ unsigned short sB[64][SPA];     // 8.5 KB col-view s2m (bf16)
    __shared__ float mrg[768];                 // 3 KB merge scratch

    // XCD-bijective swizzle (2080 % 8 == 0) + triangular decode (i <= j)
    const int orig = blockIdx.x;
    const int bid  = (orig & 7) * (NTRI / 8) + (orig >> 3);
    int j = (int)((sqrtf(8.0f * (float)bid + 1.0f) - 1.0f) * 0.5f);
    while (((j + 1) * (j + 2)) / 2 <= bid) ++j;   // fixup fp error (exact)
    while ((j * (j + 1)) / 2 > bid) --j;
    const int i = bid - (j * (j + 1)) / 2;
    const bool diag = (i == j);

    const int tid = threadIdx.x;
    const int l  = tid & 63;
    const int w  = tid >> 6;                   // 0..7
    const int wm = w >> 1, wn = w & 1;
    const int lc = l & 15;                     // frag row/col within 16
    const int lk = l >> 4;                     // k-group
    const int r64 = i * 64, c64 = j * 64;

    const s8v* hb8 = (const s8v*)hb;           // 16 x s8v per row of 128 bf16

    // ---- stage B tile: 128 hb-rows (64 pair-cols x 2 halves); 4 gloads/wave
    #pragma unroll
    for (int i2 = 0; i2 < 4; i2++) {
        const int rowb = w * 16 + i2 * 4;
        const int lrw  = rowb + lk;            // local row 0..127
        const int grow = c64 + ((lrw < 64) ? lrw : (lrw - 64 + B_ROWS));
        const int sc16 = lc ^ (lrw & 7);       // source pre-swizzle
        gload_lds16((const char*)hb + ((size_t)grow << 8) + (sc16 << 4),
                    (char*)&ldsB[rowb][0]);
    }

    // ---- stage S panels as bf16 s2m; sB = transposed block S[j-range, i-range]
    {
        const int rr = tid >> 3;               // 0..63
        const int c8 = (tid & 7) * 8;          // 0..56
        const float* gA = S + (size_t)(r64 + rr) * B_ROWS + c64 + c8;
        const float* gB = S + (size_t)(c64 + rr) * B_ROWS + r64 + c8;
        f4v a0 = ((const f4v*)gA)[0], a1 = ((const f4v*)gA)[1];
        f4v b0 = ((const f4v*)gB)[0], b1 = ((const f4v*)gB)[1];
        u16x4 pa0, pa1, pb0, pb1;
        #pragma unroll
        for (int e = 0; e < 4; e++) {
            pa0[e] = s2m_pack(a0[e], diag && (c8 + e     == rr));
            pa1[e] = s2m_pack(a1[e], diag && (c8 + 4 + e == rr));
            pb0[e] = s2m_pack(b0[e], false);   // col-view discarded on diag
            pb1[e] = s2m_pack(b1[e], false);
        }
        *(u16x4*)&sA[rr][c8]     = pa0;
        *(u16x4*)&sA[rr][c8 + 4] = pa1;
        *(u16x4*)&sB[rr][c8]     = pb0;
        *(u16x4*)&sB[rr][c8 + 4] = pb1;
    }

    // ---- A fragments: wave's 16 pair-rows x 2 halves
    s8v afr[2][4];
    #pragma unroll
    for (int fm = 0; fm < 2; fm++) {
        int ar = (r64 + wm * 16 + lc) + fm * B_ROWS;
        #pragma unroll
        for (int kk = 0; kk < 4; kk++)
            afr[fm][kk] = hb8[ar * 16 + kk * 4 + lk];
    }
    __syncthreads();   // B tile + panels + afr ready

    // ---- MFMA: 32 per wave (fm2 x fh2 x cg2 x kk4), acc[fm][fh][cg]
    const char* bp[4];
    {
        const char* bb = (const char*)ldsB + (wn * 32 + lc) * 256;
        #pragma unroll
        for (int kk = 0; kk < 4; kk++)
            bp[kk] = bb + (((kk * 4 + lk) ^ (lc & 7)) << 4);
    }
    f4v acc[2][2][2];
    #pragma unroll
    for (int fm = 0; fm < 2; fm++)
        #pragma unroll
        for (int fh = 0; fh < 2; fh++)
            #pragma unroll
            for (int cg = 0; cg < 2; cg++) acc[fm][fh][cg] = f4v{0.f, 0.f, 0.f, 0.f};
    #pragma unroll
    for (int kk = 0; kk < 4; kk++) {
        #pragma unroll
        for (int fh = 0; fh < 2; fh++)
            #pragma unroll
            for (int cg = 0; cg < 2; cg++) {
                s8v bf = *(const s8v*)(bp[kk] + fh * 16384 + cg * 4096);
                acc[0][fh][cg] = __builtin_amdgcn_mfma_f32_16x16x32_bf16(
                    afr[0][kk], bf, acc[0][fh][cg], 0, 0, 0);
                acc[1][fh][cg] = __builtin_amdgcn_mfma_f32_16x16x32_bf16(
                    afr[1][kk], bf, acc[1][fh][cg], 0, 0, 0);
            }
    }

    // ---- dual epilogue: row-view (sA[rr][cc]) + col-view (sB[cc][rr])
    float rsum[2][4], csum[2][2];
    #pragma unroll
    for (int fm = 0; fm < 2; fm++)
        #pragma unroll
        for (int r = 0; r < 4; r++) rsum[fm][r] = 0.f;
    csum[0][0] = csum[0][1] = csum[1][0] = csum[1][1] = 0.f;

    #pragma unroll
    for (int r = 0; r < 4; r++) {
        const int rr = wm * 16 + lk * 4 + r;
        #pragma unroll
        for (int cg = 0; cg < 2; cg++) {
            const int cc = wn * 32 + cg * 16 + lc;
            const float s2a = bf16f(sA[rr][cc]);
            const float s2b = bf16f(sB[cc][rr]);
            #pragma unroll
            for (int fm = 0; fm < 2; fm++)
                #pragma unroll
                for (int fh = 0; fh < 2; fh++) {
                    const float a = acc[fm][fh][cg][r];
                    rsum[fm][r]  += fast_exp2(fmaf(a, s2a, -CSHIFT));
                    csum[fh][cg] += fast_exp2(fmaf(a, s2b, -CSHIFT));
                }
        }
    }

    // ---- row reduce (over lc) -> mrg[0..255]; col reduce (over lk) -> mrg[256..767]
    #pragma unroll
    for (int fm = 0; fm < 2; fm++) {
        #pragma unroll
        for (int r = 0; r < 4; r++) {
            float ss = rsum[fm][r];
            #pragma unroll
            for (int off = 1; off < 16; off <<= 1) ss += __shfl_xor(ss, off, 64);
            if (lc == 0) mrg[wn * 128 + fm * 64 + (wm * 16 + lk * 4 + r)] = ss;
        }
    }
    #pragma unroll
    for (int fh = 0; fh < 2; fh++) {
        #pragma unroll
        for (int cg = 0; cg < 2; cg++) {
            float ss = csum[fh][cg];
            ss += __shfl_xor(ss, 16, 64);
            ss += __shfl_xor(ss, 32, 64);
            if (l < 16) mrg[256 + wm * 128 + fh * 64 + (wn * 32 + cg * 16 + lc)] = ss;
        }
    }
    __syncthreads();

    if (tid < 128) {                 // row-view -> split j, rows of tile i
        int fm = tid >> 6, rho = tid & 63;
        float v = mrg[fm * 64 + rho] + mrg[128 + fm * 64 + rho];
        ssplit[(size_t)j * NN + (r64 + rho + fm * B_ROWS)] = v;
    } else if (!diag && tid < 256) { // col-view -> split i, rows of tile j
        int t2 = tid - 128, fh = t2 >> 6, cc = t2 & 63;
        float v = mrg[256 +   0 + fh * 64 + cc] + mrg[256 + 128 + fh * 64 + cc]
                + mrg[256 + 256 + fh * 64 + cc] + mrg[256 + 384 + fh * 64 + cc];
        ssplit[(size_t)i * NN + (c64 + cc + fh * B_ROWS)] = v;
    }
}

// ---- kernel 3a: parallel split-sum + lse ----
// 256 blocks x 256 thr; block b owns rows [32b, 32b+32); thread (r=tid&31,
// s=tid>>5) sums splits sp==s mod 8 (8 loads, 128B-contiguous over n).
// LDS reduce 8 slices -> per-row lse -> block partial (fixed order).
__global__ __launch_bounds__(256)
void reduce_kernel(const float* __restrict__ ssplit, const float* __restrict__ pos2,
                   float* __restrict__ partial) {
    __shared__ float red[256];
    const int r = threadIdx.x & 31;
    const int s = threadIdx.x >> 5;
    const int n = blockIdx.x * 32 + r;              // n < 8192
    float ssum = 0.f;
    #pragma unroll
    for (int k = 0; k < 8; k++)
        ssum += ssplit[(size_t)(s + 8 * k) * NN + n];
    red[threadIdx.x] = ssum;
    __syncthreads();
    if (threadIdx.x < 32) {
        float t = 0.f;
        #pragma unroll
        for (int k = 0; k < 8; k++) t += red[threadIdx.x + 32 * k];
        float p = pos2[n & (B_ROWS - 1)];
        float Ssum = t + fast_exp2(p - CSHIFT);     // pos logit seeds the sum
        red[threadIdx.x] = (CSHIFT + log2f(Ssum)) - p;  // log2 units
    }
    __syncthreads();
    if (threadIdx.x == 0) {
        float acc = 0.f;
        #pragma unroll
        for (int k = 0; k < 32; k++) acc += red[k];
        partial[blockIdx.x] = acc;
    }
}

// ---- kernel 3b: deterministic final sum over 256 partials (LDS tree) ----
__global__ __launch_bounds__(256)
void final_kernel(const float* __restrict__ partial, float* __restrict__ out) {
    __shared__ float red[256];
    red[threadIdx.x] = partial[threadIdx.x];
    __syncthreads();
    for (int st = 128; st; st >>= 1) {
        if (threadIdx.x < st) red[threadIdx.x] += red[threadIdx.x + st];
        __syncthreads();
    }
    if (threadIdx.x == 0) out[0] = red[0] * (LN2 / (float)NN);
}

extern "C" void kernel_launch(void* const* d_in, const int* in_sizes, int n_in,
                              void* d_out, int out_size, void* d_ws, size_t ws_size,
                              hipStream_t stream) {
    (void)in_sizes; (void)n_in; (void)out_size; (void)ws_size;
    const float* hi = (const float*)d_in[0];
    const float* hj = (const float*)d_in[1];
    const float* S  = (const float*)d_in[2];

    char* ws = (char*)d_ws;
    __hip_bfloat16* hb = (__hip_bfloat16*)ws;                        // 2 MB
    float* pos2   = (float*)(ws + 2097152);                          // 16 KB
    float* ssplit = (float*)(ws + 2097152 + 16384);                  // 2 MB (64 splits)
    float* partial= (float*)(ws + 2097152 + 16384 + 2097152);        // 1 KB

    hpos_kernel<<<1024, 256, 0, stream>>>(hi, hj, hb, pos2);
    main_kernel<<<NTRI, 512, 0, stream>>>(hb, S, ssplit);
    reduce_kernel<<<256, 256, 0, stream>>>(ssplit, pos2, partial);
    final_kernel<<<1, 256, 0, stream>>>(partial, (float*)d_out);
}